// Round 5
// baseline (617.446 us; speedup 1.0000x reference)
//
#include <hip/hip_runtime.h>
#include <hip/hip_bf16.h>

#define B_   16
#define T_   2048
#define E_   1024
#define S_   2000
#define HID_ 150
#define GI_  3072

typedef __attribute__((ext_vector_type(8))) short short8;   // 8 bf16 (4 VGPRs)
typedef __attribute__((ext_vector_type(4))) float f32x4;

constexpr int NPAD = 160;        // HID padded to 10 MFMA col-tiles
constexpr int LSTR = 168;        // LDS row stride (bf16): 336 B, 16B-aligned
constexpr int MROWS = 64;        // rows per MLP block

__device__ inline short8 pack8(float4 a, float4 b) {
    union { __hip_bfloat162 h[4]; short8 s; } u;
    u.h[0] = __float22bfloat162_rn(make_float2(a.x, a.y));
    u.h[1] = __float22bfloat162_rn(make_float2(a.z, a.w));
    u.h[2] = __float22bfloat162_rn(make_float2(b.x, b.y));
    u.h[3] = __float22bfloat162_rn(make_float2(b.z, b.w));
    return u.s;
}

// W [K x 150] f32  ->  Wt [160][DSTK] bf16, zero-padded (n>=150 or k>=SRCK)
template<int SRCK, int DSTK>
__global__ __launch_bounds__(256)
void transpose_w(const float* __restrict__ src, __hip_bfloat16* __restrict__ dst) {
    int i = blockIdx.x * 256 + threadIdx.x;      // i = n*DSTK + k
    if (i >= NPAD * DSTK) return;
    int n = i / DSTK, k = i - n * DSTK;
    float v = (n < HID_ && k < SRCK) ? src[(long long)k * HID_ + n] : 0.f;
    dst[i] = __float2bfloat16(v);
}

// Full MLP: K1 -> 150 (relu) -> 150 (relu) -> 1, MROWS rows/block, 8 waves.
// Wave w: rows [(w>>1)*16, +16), cols [(w&1)*80, +80).
template<int K1>
__global__ __launch_bounds__(512, 4)
void mlp_mfma(const float* __restrict__ xin,
              const __hip_bfloat16* __restrict__ Wt1, const float* __restrict__ b1,
              const __hip_bfloat16* __restrict__ Wt2, const float* __restrict__ b2,
              const float* __restrict__ W3, const float* __restrict__ b3,
              float* __restrict__ outp)
{
    __shared__ __hip_bfloat16 hl[MROWS * LSTR];

    const int tid  = threadIdx.x;
    const int lane = tid & 63;
    const int w    = tid >> 6;          // wave 0..7
    const int rg   = w >> 1;            // row group (16 rows)
    const int cg   = w & 1;             // col group (80 cols)
    const int lr   = lane & 15;         // fragment row/col index
    const int hi   = lane >> 4;         // 0..3
    const int lk   = hi * 8;            // fragment k offset

    const long long row0 = (long long)blockIdx.x * MROWS;

    // ---------------- stage 1: K1 -> 160 (MFMA) ----------------
    f32x4 acc[5];
#pragma unroll
    for (int nt = 0; nt < 5; ++nt) acc[nt] = (f32x4){0.f, 0.f, 0.f, 0.f};

    const float* xrow = xin + (row0 + rg * 16 + lr) * K1;
    const __hip_bfloat16* brow[5];
#pragma unroll
    for (int nt = 0; nt < 5; ++nt)
        brow[nt] = Wt1 + (long long)(cg * 80 + nt * 16 + lr) * K1;

    for (int ks = 0; ks < K1 / 32; ++ks) {
        const int k0 = ks * 32 + lk;
        short8 bfr[5];
#pragma unroll
        for (int nt = 0; nt < 5; ++nt)
            bfr[nt] = *(const short8*)(brow[nt] + k0);
        float4 a0 = *(const float4*)(xrow + k0);
        float4 a1 = *(const float4*)(xrow + k0 + 4);
        short8 afr = pack8(a0, a1);
#pragma unroll
        for (int nt = 0; nt < 5; ++nt)
            acc[nt] = __builtin_amdgcn_mfma_f32_16x16x32_bf16(
                afr, bfr[nt], acc[nt], 0, 0, 0);
    }

    // bias + relu -> hl (bf16)
#pragma unroll
    for (int nt = 0; nt < 5; ++nt) {
        const int ch = cg * 80 + nt * 16 + lr;
        const float bb = (ch < HID_) ? b1[ch] : 0.f;
#pragma unroll
        for (int r = 0; r < 4; ++r) {
            const int row = rg * 16 + hi * 4 + r;
            float h = acc[nt][r] + bb;
            hl[row * LSTR + ch] = __float2bfloat16(h > 0.f ? h : 0.f);
        }
    }
    __syncthreads();

    // ---------------- stage 2: 160 -> 160 (MFMA, K=160) ----------------
    f32x4 acc2[5];
#pragma unroll
    for (int nt = 0; nt < 5; ++nt) acc2[nt] = (f32x4){0.f, 0.f, 0.f, 0.f};

#pragma unroll
    for (int ks = 0; ks < 5; ++ks) {
        const int k0 = ks * 32 + lk;
        short8 bfr[5];
#pragma unroll
        for (int nt = 0; nt < 5; ++nt)
            bfr[nt] = *(const short8*)(Wt2 + (cg * 80 + nt * 16 + lr) * NPAD + k0);
        short8 afr = *(const short8*)(&hl[(rg * 16 + lr) * LSTR + k0]);
#pragma unroll
        for (int nt = 0; nt < 5; ++nt)
            acc2[nt] = __builtin_amdgcn_mfma_f32_16x16x32_bf16(
                afr, bfr[nt], acc2[nt], 0, 0, 0);
    }
    __syncthreads();   // stage-2 reads done before overwrite

    // bias + relu -> hl (h2)
#pragma unroll
    for (int nt = 0; nt < 5; ++nt) {
        const int ch = cg * 80 + nt * 16 + lr;
        const float bb = (ch < HID_) ? b2[ch] : 0.f;
#pragma unroll
        for (int r = 0; r < 4; ++r) {
            const int row = rg * 16 + hi * 4 + r;
            float h = acc2[nt][r] + bb;
            hl[row * LSTR + ch] = __float2bfloat16(h > 0.f ? h : 0.f);
        }
    }
    __syncthreads();

    // ---------------- stage 3: 150 -> 1 (8 threads per row) ----------------
    {
        const int row = tid >> 3, oct = tid & 7;
        const int kb = oct * 19;
        const int ke = (kb + 19 > HID_) ? HID_ : kb + 19;
        float s = 0.f;
        for (int k = kb; k < ke; ++k)
            s += __bfloat162float(hl[row * LSTR + k]) * W3[k];
        s += __shfl_xor(s, 1);
        s += __shfl_xor(s, 2);
        s += __shfl_xor(s, 4);
        if (oct == 0) outp[row0 + row] = s + b3[0];
    }
}

// span_emb = [x[start], x[end], sum_{t=start..end} x[t]*attn[t]]  (f32 out)
__global__ __launch_bounds__(256)
void span_kernel(const float* __restrict__ x, const float* __restrict__ attn,
                 const int* __restrict__ starts, const int* __restrict__ lengths,
                 const int* __restrict__ nspans, float* __restrict__ out)
{
    const int blk = blockIdx.x;        // b*S + s
    const int b = blk / S_;
    const int s = blk - b * S_;
    const int tid = threadIdx.x;       // each thread: 4 consecutive elements
    float* orow = out + (long long)blk * (3 * E_);

    if (s >= nspans[b]) {
        float4 z = make_float4(0.f, 0.f, 0.f, 0.f);
        *(float4*)(orow + tid * 4)          = z;
        *(float4*)(orow + E_ + tid * 4)     = z;
        *(float4*)(orow + 2 * E_ + tid * 4) = z;
        return;
    }
    const int st = starts[blk];
    const int en = st + lengths[blk];   // inclusive end index, < T
    const float* xb = x + (long long)b * T_ * E_;

    float4 vs = *(const float4*)(xb + (long long)st * E_ + tid * 4);
    float4 ve = *(const float4*)(xb + (long long)en * E_ + tid * 4);
    *(float4*)(orow + tid * 4)      = vs;   // bit-exact g_start
    *(float4*)(orow + E_ + tid * 4) = ve;   // bit-exact g_end

    float4 a4 = make_float4(0.f, 0.f, 0.f, 0.f);
    const float* ab = attn + b * T_;
    for (int t = st; t <= en; ++t) {
        float a = ab[t];
        float4 v = *(const float4*)(xb + (long long)t * E_ + tid * 4);
        a4.x += v.x * a; a4.y += v.y * a; a4.z += v.z * a; a4.w += v.w * a;
    }
    *(float4*)(orow + 2 * E_ + tid * 4) = a4;
}

extern "C" void kernel_launch(void* const* d_in, const int* in_sizes, int n_in,
                              void* d_out, int out_size, void* d_ws, size_t ws_size,
                              hipStream_t stream) {
    const float* x       = (const float*)d_in[0];
    const int*   starts  = (const int*)d_in[1];
    const int*   lengths = (const int*)d_in[2];
    const int*   nspans  = (const int*)d_in[3];
    const float* Wa1 = (const float*)d_in[4];
    const float* ba1 = (const float*)d_in[5];
    const float* Wa2 = (const float*)d_in[6];
    const float* ba2 = (const float*)d_in[7];
    const float* Wa3 = (const float*)d_in[8];
    const float* ba3 = (const float*)d_in[9];
    const float* Ws1 = (const float*)d_in[10];
    const float* bs1 = (const float*)d_in[11];
    const float* Ws2 = (const float*)d_in[12];
    const float* bs2 = (const float*)d_in[13];
    const float* Ws3 = (const float*)d_in[14];
    const float* bs3 = (const float*)d_in[15];

    float* out        = (float*)d_out;                       // span_emb [B,S,3E]
    float* out_scores = out + (long long)B_ * S_ * 3 * E_;   // scores [B,S]

    // workspace layout (16B-aligned offsets)
    char* ws = (char*)d_ws;
    float*          attn = (float*)ws;                         // 131072 B
    __hip_bfloat16* Wt1a = (__hip_bfloat16*)(ws + 131072);     // 160*1024*2
    __hip_bfloat16* Wt2a = (__hip_bfloat16*)(ws + 458752);     // 160*160*2
    __hip_bfloat16* Wt1s = (__hip_bfloat16*)(ws + 509952);     // 160*3072*2
    __hip_bfloat16* Wt2s = (__hip_bfloat16*)(ws + 1492992);    // 160*160*2

    // 0) pre-transpose weights to bf16 [NPAD][K]
    transpose_w<E_,  E_ ><<<(NPAD * E_ ) / 256, 256, 0, stream>>>(Wa1, Wt1a);
    transpose_w<HID_,NPAD><<<(NPAD * NPAD) / 256, 256, 0, stream>>>(Wa2, Wt2a);
    transpose_w<GI_, GI_ ><<<(NPAD * GI_ ) / 256, 256, 0, stream>>>(Ws1, Wt1s);
    transpose_w<HID_,NPAD><<<(NPAD * NPAD) / 256, 256, 0, stream>>>(Ws2, Wt2s);

    // 1) attention score per token (32768 rows, 512 blocks)
    mlp_mfma<E_><<<(B_ * T_) / MROWS, 512, 0, stream>>>
        (x, Wt1a, ba1, Wt2a, ba2, Wa3, ba3, attn);

    // 2) span embeddings (direct ragged sum; lengths < 24)
    span_kernel<<<B_ * S_, 256, 0, stream>>>(x, attn, starts, lengths, nspans, out);

    // 3) mention scores from span_emb (32000 rows, 500 blocks)
    mlp_mfma<GI_><<<(B_ * S_) / MROWS, 512, 0, stream>>>
        (out, Wt1s, bs1, Wt2s, bs2, Ws3, bs3, out_scores);
}

// Round 6
// 524.525 us; speedup vs baseline: 1.1772x; 1.1772x over previous
//
#include <hip/hip_runtime.h>
#include <hip/hip_bf16.h>

#define B_   16
#define T_   2048
#define E_   1024
#define S_   2000
#define HID_ 150
#define GI_  3072

typedef __attribute__((ext_vector_type(8))) short short8;   // 8 bf16 (4 VGPRs)
typedef __attribute__((ext_vector_type(4))) float f32x4;

constexpr int NPAD  = 160;   // HID padded to 10 MFMA col-tiles
constexpr int LSTR  = 168;   // hl row stride (bf16): 336 B -> conflict-free b128
constexpr int MROWS = 64;    // rows per MLP block
constexpr int SSTR  = 68;    // A-stage row stride (floats): 272 B -> uniform banks

__device__ inline short8 pack8(float4 a, float4 b) {
    union { __hip_bfloat162 h[4]; short8 s; } u;
    u.h[0] = __float22bfloat162_rn(make_float2(a.x, a.y));
    u.h[1] = __float22bfloat162_rn(make_float2(a.z, a.w));
    u.h[2] = __float22bfloat162_rn(make_float2(b.x, b.y));
    u.h[3] = __float22bfloat162_rn(make_float2(b.z, b.w));
    return u.s;
}

// W [K x 150] f32  ->  Wt [160][DSTK] bf16, zero-padded (n>=150 or k>=SRCK)
template<int SRCK, int DSTK>
__global__ __launch_bounds__(256)
void transpose_w(const float* __restrict__ src, __hip_bfloat16* __restrict__ dst) {
    int i = blockIdx.x * 256 + threadIdx.x;      // i = n*DSTK + k
    if (i >= NPAD * DSTK) return;
    int n = i / DSTK, k = i - n * DSTK;
    float v = (n < HID_ && k < SRCK) ? src[(long long)k * HID_ + n] : 0.f;
    dst[i] = __float2bfloat16(v);
}

// Full MLP: K1 -> 150 (relu) -> 150 (relu) -> 1, MROWS rows/block, 8 waves.
// Stage 1: A staged via padded LDS double-buffer (coalesced), MFMA bf16.
template<int K1>
__global__ __launch_bounds__(512, 4)
void mlp_mfma(const float* __restrict__ xin,
              const __hip_bfloat16* __restrict__ Wt1, const float* __restrict__ b1,
              const __hip_bfloat16* __restrict__ Wt2, const float* __restrict__ b2,
              const float* __restrict__ W3, const float* __restrict__ b3,
              float* __restrict__ outp)
{
    constexpr int NC = K1 / 64;                 // 64-float K-chunks
    __shared__ float sA[2][MROWS * SSTR];       // 2 x 17.4 KB
    __shared__ __hip_bfloat16 hl[MROWS * LSTR]; // 21.5 KB

    const int tid  = threadIdx.x;
    const int lane = tid & 63;
    const int w    = tid >> 6;          // wave 0..7
    const int rg   = w >> 1;            // row group (16 rows)
    const int cg   = w & 1;             // col group (80 cols)
    const int lr   = lane & 15;
    const int hi   = lane >> 4;         // 0..3
    const int lk   = hi * 8;

    const long long row0 = (long long)blockIdx.x * MROWS;

    // staging: 1024 granules (64 rows x 16 float4s); thread covers 2
    const int jr0 = tid >> 4, jq = tid & 15;    // granule tid
    const int jr1 = jr0 + 32;                   // granule tid+512
    const float* g0 = xin + (row0 + jr0) * (long long)K1 + jq * 4;
    const float* g1 = xin + (row0 + jr1) * (long long)K1 + jq * 4;
    const int l0 = jr0 * SSTR + jq * 4;         // LDS float index (per buffer)
    const int l1 = jr1 * SSTR + jq * 4;

    // ---------------- stage 1: K1 -> 160 (MFMA, staged A) ----------------
    f32x4 acc[5];
#pragma unroll
    for (int nt = 0; nt < 5; ++nt) acc[nt] = (f32x4){0.f, 0.f, 0.f, 0.f};

    const __hip_bfloat16* brow[5];
#pragma unroll
    for (int nt = 0; nt < 5; ++nt)
        brow[nt] = Wt1 + (long long)(cg * 80 + nt * 16 + lr) * K1;

    // prologue: chunk 0 into buf 0
    {
        float4 p0 = *(const float4*)(g0);
        float4 p1 = *(const float4*)(g1);
        *(float4*)(&sA[0][l0]) = p0;
        *(float4*)(&sA[0][l1]) = p1;
    }

    for (int c = 0; c < NC; ++c) {
        const int bi = c & 1;
        __syncthreads();   // buf[bi] ready; all reads of buf[bi^1] finished

        // load phase: B fragments (L2) + A fragments (LDS)
        short8 bfr[2][5];
        float4 a0[2], a1[2];
#pragma unroll
        for (int ks = 0; ks < 2; ++ks) {
            const int kg = c * 64 + ks * 32 + lk;
#pragma unroll
            for (int nt = 0; nt < 5; ++nt)
                bfr[ks][nt] = *(const short8*)(brow[nt] + kg);
            const float* ar = &sA[bi][(rg * 16 + lr) * SSTR + ks * 32 + lk];
            a0[ks] = *(const float4*)(ar);
            a1[ks] = *(const float4*)(ar + 4);
        }
        // prefetch next chunk (issued after B-loads: MFMA waits vmcnt(2), not 0)
        float4 n0, n1;
        const bool more = (c + 1 < NC);
        if (more) {
            n0 = *(const float4*)(g0 + (c + 1) * 64);
            n1 = *(const float4*)(g1 + (c + 1) * 64);
        }
        // mfma phase
#pragma unroll
        for (int ks = 0; ks < 2; ++ks) {
            short8 afr = pack8(a0[ks], a1[ks]);
#pragma unroll
            for (int nt = 0; nt < 5; ++nt)
                acc[nt] = __builtin_amdgcn_mfma_f32_16x16x32_bf16(
                    afr, bfr[ks][nt], acc[nt], 0, 0, 0);
        }
        // write phase: stage next chunk into the other buffer
        if (more) {
            *(float4*)(&sA[bi ^ 1][l0]) = n0;
            *(float4*)(&sA[bi ^ 1][l1]) = n1;
        }
    }

    // bias + relu -> hl (bf16)
#pragma unroll
    for (int nt = 0; nt < 5; ++nt) {
        const int ch = cg * 80 + nt * 16 + lr;
        const float bb = (ch < HID_) ? b1[ch] : 0.f;
#pragma unroll
        for (int r = 0; r < 4; ++r) {
            const int row = rg * 16 + hi * 4 + r;
            float h = acc[nt][r] + bb;
            hl[row * LSTR + ch] = __float2bfloat16(h > 0.f ? h : 0.f);
        }
    }
    __syncthreads();

    // ---------------- stage 2: 160 -> 160 (MFMA, K=160) ----------------
    f32x4 acc2[5];
#pragma unroll
    for (int nt = 0; nt < 5; ++nt) acc2[nt] = (f32x4){0.f, 0.f, 0.f, 0.f};

#pragma unroll
    for (int ks = 0; ks < 5; ++ks) {
        const int k0 = ks * 32 + lk;
        short8 bfr[5];
#pragma unroll
        for (int nt = 0; nt < 5; ++nt)
            bfr[nt] = *(const short8*)(Wt2 + (cg * 80 + nt * 16 + lr) * NPAD + k0);
        short8 afr = *(const short8*)(&hl[(rg * 16 + lr) * LSTR + k0]);
#pragma unroll
        for (int nt = 0; nt < 5; ++nt)
            acc2[nt] = __builtin_amdgcn_mfma_f32_16x16x32_bf16(
                afr, bfr[nt], acc2[nt], 0, 0, 0);
    }
    __syncthreads();   // stage-2 reads done before overwrite

    // bias + relu -> hl (h2)
#pragma unroll
    for (int nt = 0; nt < 5; ++nt) {
        const int ch = cg * 80 + nt * 16 + lr;
        const float bb = (ch < HID_) ? b2[ch] : 0.f;
#pragma unroll
        for (int r = 0; r < 4; ++r) {
            const int row = rg * 16 + hi * 4 + r;
            float h = acc2[nt][r] + bb;
            hl[row * LSTR + ch] = __float2bfloat16(h > 0.f ? h : 0.f);
        }
    }
    __syncthreads();

    // ---------------- stage 3: 150 -> 1 (8 threads per row) ----------------
    {
        const int row = tid >> 3, oct = tid & 7;
        const int kb = oct * 19;
        const int ke = (kb + 19 > HID_) ? HID_ : kb + 19;
        float s = 0.f;
        for (int k = kb; k < ke; ++k)
            s += __bfloat162float(hl[row * LSTR + k]) * W3[k];
        s += __shfl_xor(s, 1);
        s += __shfl_xor(s, 2);
        s += __shfl_xor(s, 4);
        if (oct == 0) outp[row0 + row] = s + b3[0];
    }
}

// span_emb = [x[start], x[end], sum_{t=start..end} x[t]*attn[t]]  (f32 out)
__global__ __launch_bounds__(256)
void span_kernel(const float* __restrict__ x, const float* __restrict__ attn,
                 const int* __restrict__ starts, const int* __restrict__ lengths,
                 const int* __restrict__ nspans, float* __restrict__ out)
{
    const int blk = blockIdx.x;        // b*S + s
    const int b = blk / S_;
    const int s = blk - b * S_;
    const int tid = threadIdx.x;       // each thread: 4 consecutive elements
    float* orow = out + (long long)blk * (3 * E_);

    if (s >= nspans[b]) {
        float4 z = make_float4(0.f, 0.f, 0.f, 0.f);
        *(float4*)(orow + tid * 4)          = z;
        *(float4*)(orow + E_ + tid * 4)     = z;
        *(float4*)(orow + 2 * E_ + tid * 4) = z;
        return;
    }
    const int st = starts[blk];
    const int en = st + lengths[blk];   // inclusive end index, < T
    const float* xb = x + (long long)b * T_ * E_;

    float4 vs = *(const float4*)(xb + (long long)st * E_ + tid * 4);
    float4 ve = *(const float4*)(xb + (long long)en * E_ + tid * 4);
    *(float4*)(orow + tid * 4)      = vs;   // bit-exact g_start
    *(float4*)(orow + E_ + tid * 4) = ve;   // bit-exact g_end

    float4 a4 = make_float4(0.f, 0.f, 0.f, 0.f);
    const float* ab = attn + b * T_;
    for (int t = st; t <= en; ++t) {
        float a = ab[t];
        float4 v = *(const float4*)(xb + (long long)t * E_ + tid * 4);
        a4.x += v.x * a; a4.y += v.y * a; a4.z += v.z * a; a4.w += v.w * a;
    }
    *(float4*)(orow + 2 * E_ + tid * 4) = a4;
}

extern "C" void kernel_launch(void* const* d_in, const int* in_sizes, int n_in,
                              void* d_out, int out_size, void* d_ws, size_t ws_size,
                              hipStream_t stream) {
    const float* x       = (const float*)d_in[0];
    const int*   starts  = (const int*)d_in[1];
    const int*   lengths = (const int*)d_in[2];
    const int*   nspans  = (const int*)d_in[3];
    const float* Wa1 = (const float*)d_in[4];
    const float* ba1 = (const float*)d_in[5];
    const float* Wa2 = (const float*)d_in[6];
    const float* ba2 = (const float*)d_in[7];
    const float* Wa3 = (const float*)d_in[8];
    const float* ba3 = (const float*)d_in[9];
    const float* Ws1 = (const float*)d_in[10];
    const float* bs1 = (const float*)d_in[11];
    const float* Ws2 = (const float*)d_in[12];
    const float* bs2 = (const float*)d_in[13];
    const float* Ws3 = (const float*)d_in[14];
    const float* bs3 = (const float*)d_in[15];

    float* out        = (float*)d_out;                       // span_emb [B,S,3E]
    float* out_scores = out + (long long)B_ * S_ * 3 * E_;   // scores [B,S]

    // workspace layout (16B-aligned offsets)
    char* ws = (char*)d_ws;
    float*          attn = (float*)ws;                         // 131072 B
    __hip_bfloat16* Wt1a = (__hip_bfloat16*)(ws + 131072);     // 160*1024*2
    __hip_bfloat16* Wt2a = (__hip_bfloat16*)(ws + 458752);     // 160*160*2
    __hip_bfloat16* Wt1s = (__hip_bfloat16*)(ws + 509952);     // 160*3072*2
    __hip_bfloat16* Wt2s = (__hip_bfloat16*)(ws + 1492992);    // 160*160*2

    // 0) pre-transpose weights to bf16 [NPAD][K]
    transpose_w<E_,  E_ ><<<(NPAD * E_ ) / 256, 256, 0, stream>>>(Wa1, Wt1a);
    transpose_w<HID_,NPAD><<<(NPAD * NPAD) / 256, 256, 0, stream>>>(Wa2, Wt2a);
    transpose_w<GI_, GI_ ><<<(NPAD * GI_ ) / 256, 256, 0, stream>>>(Ws1, Wt1s);
    transpose_w<HID_,NPAD><<<(NPAD * NPAD) / 256, 256, 0, stream>>>(Ws2, Wt2s);

    // 1) attention score per token (32768 rows, 512 blocks)
    mlp_mfma<E_><<<(B_ * T_) / MROWS, 512, 0, stream>>>
        (x, Wt1a, ba1, Wt2a, ba2, Wa3, ba3, attn);

    // 2) span embeddings (direct ragged sum; lengths < 24)
    span_kernel<<<B_ * S_, 256, 0, stream>>>(x, attn, starts, lengths, nspans, out);

    // 3) mention scores from span_emb (32000 rows, 500 blocks)
    mlp_mfma<GI_><<<(B_ * S_) / MROWS, 512, 0, stream>>>
        (out, Wt1s, bs1, Wt2s, bs2, Ws3, bs3, out_scores);
}